// Round 13
// baseline (74.053 us; speedup 1.0000x reference)
//
#include <hip/hip_runtime.h>
#include <hip/hip_fp16.h>
#include <math.h>

#define CLIPV 0.03f

struct W9 { float g[9]; };
struct half4 { __half2 a, b; };   // 8 bytes, 2 VGPRs
typedef float nt4 __attribute__((ext_vector_type(4)));   // for nontemporal builtins

__device__ __forceinline__ int reflect_idx(int i, int n) {
    if (i < 0) i = -i;
    if (i >= n) i = 2 * n - 2 - i;
    return i;
}

__device__ __forceinline__ float4 h4_to_f4(half4 v) {
    const float2 ab = __half22float2(v.a), cd = __half22float2(v.b);
    float4 r; r.x = ab.x; r.y = ab.y; r.z = cd.x; r.w = cd.y; return r;
}
__device__ __forceinline__ half4 f4_to_h4(float4 v) {
    half4 r; r.a = __floats2half2_rn(v.x, v.y); r.b = __floats2half2_rn(v.z, v.w);
    return r;
}

// ---------------------------------------------------------------------------
// Pass 1: W-conv (x f32 -> t1 fp16). No march-axis window => no warm-up amp.
// Wave = 16 rows of one z-plane; depth-2 row pipeline (rows i+1, i+2 in
// flight; write slot (i+2)%3, read slot i%3 — disjoint). 3 overlapping f4
// loads/row (L1-hot), R5/R7-validated edge table.
// Grid: 1024 blocks x 4 waves = 4096 waves = 4 blocks/CU exactly.
// bid&7 = XCD owns z-band [32*xcd, 32*xcd+32).
// ---------------------------------------------------------------------------
__global__ __launch_bounds__(256, 4) void w_pass(const float* __restrict__ x,
                                                 __half* __restrict__ t1, W9 wt) {
    const int bid = blockIdx.x;
    const int xcd = bid & 7;
    const int k   = bid >> 3;                       // 0..127
    const int z   = xcd * 32 + (k >> 2);            // XCD-local z band
    const int wv  = threadIdx.x >> 6;
    const int h0  = ((k & 3) * 4 + wv) * 16;        // this wave's 16 rows
    const int L   = threadIdx.x & 63;
    const int w4  = L * 4;
    const bool l0 = (L == 0), l63 = (L == 63);
    const int offL = l0 ? 1 : (w4 - 4);     // lane 0 loads cols 1..4, reversed
    const int offR = l63 ? 251 : (w4 + 4);  // lane 63 loads 251..254, reversed

    const float* plane  = x  + (size_t)z * 65536;
    __half*      oplane = t1 + (size_t)z * 65536;

    float4 sL[3], sC[3], sR[3];
    {
        const float* row = plane + (size_t)h0 * 256;
        sL[0] = *(const float4*)(row + offL);
        sC[0] = *(const float4*)(row + w4);
        sR[0] = *(const float4*)(row + offR);
        row += 256;
        sL[1] = *(const float4*)(row + offL);
        sC[1] = *(const float4*)(row + w4);
        sR[1] = *(const float4*)(row + offR);
    }

    #pragma unroll
    for (int i = 0; i < 16; ++i) {
        if (i < 14) {
            const float* row = plane + (size_t)(h0 + i + 2) * 256;
            sL[(i + 2) % 3] = *(const float4*)(row + offL);
            sC[(i + 2) % 3] = *(const float4*)(row + w4);
            sR[(i + 2) % 3] = *(const float4*)(row + offR);
        }
        const float4 cL = sL[i % 3], cC = sC[i % 3], cR = sR[i % 3];

        float sv[12];
        sv[0] = l0 ? cL.w : cL.x;   // col -4 -> 4
        sv[1] = l0 ? cL.z : cL.y;   // col -3 -> 3
        sv[2] = l0 ? cL.y : cL.z;   // col -2 -> 2
        sv[3] = l0 ? cL.x : cL.w;   // col -1 -> 1
        sv[4] = cC.x; sv[5] = cC.y; sv[6] = cC.z; sv[7] = cC.w;
        sv[8]  = l63 ? cR.w : cR.x; // col 256 -> 254
        sv[9]  = l63 ? cR.z : cR.y; // col 257 -> 253
        sv[10] = l63 ? cR.y : cR.z; // col 258 -> 252
        sv[11] = l63 ? cR.x : cR.w; // col 259 -> 251

        float4 wc;
        {
            float a0 = 0.f, a1 = 0.f, a2 = 0.f, a3 = 0.f;
            #pragma unroll
            for (int j = 0; j < 9; ++j) {
                a0 = fmaf(wt.g[j], sv[j],     a0);
                a1 = fmaf(wt.g[j], sv[j + 1], a1);
                a2 = fmaf(wt.g[j], sv[j + 2], a2);
                a3 = fmaf(wt.g[j], sv[j + 3], a3);
            }
            wc.x = a0; wc.y = a1; wc.z = a2; wc.w = a3;
        }
        *(half4*)(oplane + (size_t)(h0 + i) * 256 + w4) = f4_to_h4(wc);
    }
}

// ---------------------------------------------------------------------------
// Pass 2: H-conv (t1 fp16 -> t2 fp16). Lane-local ring march over h,
// chunk 16 (24 iters / 16 outputs, amp 1.5). 9-deep f32 ring, depth-2 load
// pipeline (named cur/nxt/nn registers). Grid: 1024 x 4 waves; same XCD
// z-band as pass 1.
// ---------------------------------------------------------------------------
__global__ __launch_bounds__(256, 4) void h2_pass(const __half* __restrict__ t1,
                                                  __half* __restrict__ t2, W9 wt) {
    const int bid = blockIdx.x;
    const int xcd = bid & 7;
    const int k   = bid >> 3;                       // 0..127
    const int z   = xcd * 32 + (k >> 2);
    const int wv  = threadIdx.x >> 6;
    const int h0  = ((k & 3) * 4 + wv) * 16;        // 16 output rows
    const int w4  = (threadIdx.x & 63) * 4;

    const __half* plane  = t1 + (size_t)z * 65536;
    __half*       oplane = t2 + (size_t)z * 65536;

    float4 ring[9];

    half4 cur = *(const half4*)(plane + (size_t)reflect_idx(h0 - 4, 256) * 256 + w4);
    half4 nxt = *(const half4*)(plane + (size_t)reflect_idx(h0 - 3, 256) * 256 + w4);

    #pragma unroll
    for (int i = 0; i < 24; ++i) {
        half4 nn;
        if (i < 22)
            nn = *(const half4*)(plane + (size_t)reflect_idx(h0 - 2 + i, 256) * 256 + w4);

        ring[i % 9] = h4_to_f4(cur);   // row h0-4+i (static index after unroll)

        if (i >= 8) {
            float a0 = 0.f, a1 = 0.f, a2 = 0.f, a3 = 0.f;
            #pragma unroll
            for (int j = 0; j < 9; ++j) {
                const float4 v = ring[(i - 8 + j) % 9];
                a0 = fmaf(wt.g[j], v.x, a0);
                a1 = fmaf(wt.g[j], v.y, a1);
                a2 = fmaf(wt.g[j], v.z, a2);
                a3 = fmaf(wt.g[j], v.w, a3);
            }
            float4 o; o.x = a0; o.y = a1; o.z = a2; o.w = a3;
            *(half4*)(oplane + (size_t)(h0 + i - 8) * 256 + w4) = f4_to_h4(o);
        }

        cur = nxt; nxt = nn;
    }
}

// ---------------------------------------------------------------------------
// Pass 3: D-conv + clip (t2 fp16 + x f32 -> out f32). Thread owns one f4
// column, marches a z-chunk of 16 (24 iters, amp 1.5) with a 9-deep f32
// ring; depth-2 on t2 and on the clip-source x. HAZARD FIX (R12 bug): the
// xs[i%2] slot consumed at iter i was overwritten by the load issued at the
// top of the SAME iteration — capture the slot into a local BEFORE the load.
// out stored non-temporally (never re-read); x loaded non-temporally.
// Grid: 1024 x 4 waves; chunks 2*xcd..2*xcd+1 match the writer XCD band.
// ---------------------------------------------------------------------------
__global__ __launch_bounds__(256, 4) void d_clip_pass(const __half* __restrict__ t2,
                                                      const float* __restrict__ x,
                                                      float* __restrict__ out, W9 wt) {
    const int bid   = blockIdx.x;
    const int xcd   = bid & 7;
    const int k     = bid >> 3;                  // 0..127
    const int chunk = xcd * 2 + (k & 1);         // 0..15, XCD-local
    const int tile  = k >> 1;                    // 0..63
    const int z0    = chunk * 16;
    const size_t c4 = (size_t)tile * 256 + threadIdx.x;   // f4-col in plane

    const half4* t4 = (const half4*)t2;          // plane stride 16384 half4s
    const nt4*   xp = (const nt4*)x;
    nt4*         o4 = (nt4*)out;

    float4 ring[9];
    nt4 xs[2];

    half4 cur = t4[(size_t)reflect_idx(z0 - 4, 256) * 16384 + c4];
    half4 nxt = t4[(size_t)reflect_idx(z0 - 3, 256) * 16384 + c4];

    #pragma unroll
    for (int i = 0; i < 24; ++i) {
        // capture the x value loaded 2 iterations ago (plane z0+i-8) BEFORE
        // the slot is overwritten below (R12 hazard fix)
        const nt4 xv = xs[i % 2];

        half4 nn;
        if (i < 22)
            nn = t4[(size_t)reflect_idx(z0 - 2 + i, 256) * 16384 + c4];
        if (i >= 6 && i < 22)   // x for z0+i-6, consumed at iter i+2
            xs[i % 2] = __builtin_nontemporal_load(&xp[(size_t)(z0 + i - 6) * 16384 + c4]);

        ring[i % 9] = h4_to_f4(cur);   // plane z0-4+i

        if (i >= 8) {
            const int z = z0 + i - 8;
            float a0 = 0.f, a1 = 0.f, a2 = 0.f, a3 = 0.f;
            #pragma unroll
            for (int j = 0; j < 9; ++j) {
                const float4 v = ring[(i - 8 + j) % 9];
                a0 = fmaf(wt.g[j], v.x, a0);
                a1 = fmaf(wt.g[j], v.y, a1);
                a2 = fmaf(wt.g[j], v.z, a2);
                a3 = fmaf(wt.g[j], v.w, a3);
            }
            nt4 r;
            r.x = fmaxf(fminf(xv.x, a0 + CLIPV), a0 - CLIPV);
            r.y = fmaxf(fminf(xv.y, a1 + CLIPV), a1 - CLIPV);
            r.z = fmaxf(fminf(xv.z, a2 + CLIPV), a2 - CLIPV);
            r.w = fmaxf(fminf(xv.w, a3 + CLIPV), a3 - CLIPV);
            __builtin_nontemporal_store(r, &o4[(size_t)z * 16384 + c4]);
        }

        cur = nxt; nxt = nn;
    }
}

extern "C" void kernel_launch(void* const* d_in, const int* in_sizes, int n_in,
                              void* d_out, int out_size, void* d_ws, size_t ws_size,
                              hipStream_t stream) {
    const float* x = (const float*)d_in[0];
    float* out = (float*)d_out;
    __half* t1 = (__half*)d_ws;            // 32 MB
    __half* t2 = t1 + 16777216;            // 32 MB

    // normalized 1-D Gaussian weights (separable form of the reference kernel)
    W9 wt;
    {
        double g[9], s = 0.0;
        const double sigma = 9.0 / 4.0;
        for (int i = 0; i < 9; ++i) {
            double tt = (i - 4.0) / sigma;
            g[i] = exp(-0.5 * tt * tt);
            s += g[i];
        }
        for (int i = 0; i < 9; ++i) wt.g[i] = (float)(g[i] / s);
    }

    w_pass<<<dim3(1024), dim3(256), 0, stream>>>(x, t1, wt);
    h2_pass<<<dim3(1024), dim3(256), 0, stream>>>(t1, t2, wt);
    d_clip_pass<<<dim3(1024), dim3(256), 0, stream>>>(t2, x, out, wt);
}

// Round 14
// 65.325 us; speedup vs baseline: 1.1336x; 1.1336x over previous
//
#include <hip/hip_runtime.h>
#include <hip/hip_fp16.h>
#include <math.h>

#define CLIPV 0.03f

struct W9 { float g[9]; };
struct half4 { __half2 a, b; };   // 8 bytes, 2 VGPRs

__device__ __forceinline__ int reflect_idx(int i, int n) {
    if (i < 0) i = -i;
    if (i >= n) i = 2 * n - 2 - i;
    return i;
}

__device__ __forceinline__ float4 h4_to_f4(half4 v) {
    const float2 ab = __half22float2(v.a), cd = __half22float2(v.b);
    float4 r; r.x = ab.x; r.y = ab.y; r.z = cd.x; r.w = cd.y; return r;
}
__device__ __forceinline__ half4 f4_to_h4(float4 v) {
    half4 r; r.a = __floats2half2_rn(v.x, v.y); r.b = __floats2half2_rn(v.z, v.w);
    return r;
}

// ---------------------------------------------------------------------------
// Pass 1: W-conv (x f32 -> t1 fp16). No march-axis window => no warm-up amp.
// Wave = 8 rows of one z-plane; depth-2 row pipeline (disjoint slots).
// 3 overlapping f4 loads/row (L1-hot), R5/R7-validated edge table.
// Grid: 2048 blocks x 4 waves = 8192 waves = 32 waves/CU.
// bid&7 = XCD owns z-band [32*xcd, 32*xcd+32).
// ---------------------------------------------------------------------------
__global__ __launch_bounds__(256) void w_pass(const float* __restrict__ x,
                                              __half* __restrict__ t1, W9 wt) {
    const int bid = blockIdx.x;
    const int xcd = bid & 7;
    const int k   = bid >> 3;               // 0..255
    const int z   = xcd * 32 + (k >> 3);    // XCD-local z band
    const int wv  = threadIdx.x >> 6;
    const int h0  = (k & 7) * 32 + wv * 8;  // this wave's 8 rows
    const int L   = threadIdx.x & 63;
    const int w4  = L * 4;
    const bool l0 = (L == 0), l63 = (L == 63);
    const int offL = l0 ? 1 : (w4 - 4);     // lane 0 loads cols 1..4, reversed
    const int offR = l63 ? 251 : (w4 + 4);  // lane 63 loads 251..254, reversed

    const float* plane  = x  + (size_t)z * 65536;
    __half*      oplane = t1 + (size_t)z * 65536;

    float4 sL[3], sC[3], sR[3];
    {
        const float* row = plane + (size_t)h0 * 256;
        sL[0] = *(const float4*)(row + offL);
        sC[0] = *(const float4*)(row + w4);
        sR[0] = *(const float4*)(row + offR);
        row += 256;
        sL[1] = *(const float4*)(row + offL);
        sC[1] = *(const float4*)(row + w4);
        sR[1] = *(const float4*)(row + offR);
    }

    #pragma unroll
    for (int i = 0; i < 8; ++i) {
        if (i < 6) {
            const float* row = plane + (size_t)(h0 + i + 2) * 256;
            sL[(i + 2) % 3] = *(const float4*)(row + offL);
            sC[(i + 2) % 3] = *(const float4*)(row + w4);
            sR[(i + 2) % 3] = *(const float4*)(row + offR);
        }
        const float4 cL = sL[i % 3], cC = sC[i % 3], cR = sR[i % 3];

        float sv[12];
        sv[0] = l0 ? cL.w : cL.x;   // col -4 -> 4
        sv[1] = l0 ? cL.z : cL.y;   // col -3 -> 3
        sv[2] = l0 ? cL.y : cL.z;   // col -2 -> 2
        sv[3] = l0 ? cL.x : cL.w;   // col -1 -> 1
        sv[4] = cC.x; sv[5] = cC.y; sv[6] = cC.z; sv[7] = cC.w;
        sv[8]  = l63 ? cR.w : cR.x; // col 256 -> 254
        sv[9]  = l63 ? cR.z : cR.y; // col 257 -> 253
        sv[10] = l63 ? cR.y : cR.z; // col 258 -> 252
        sv[11] = l63 ? cR.x : cR.w; // col 259 -> 251

        float4 wc;
        {
            float a0 = 0.f, a1 = 0.f, a2 = 0.f, a3 = 0.f;
            #pragma unroll
            for (int j = 0; j < 9; ++j) {
                a0 = fmaf(wt.g[j], sv[j],     a0);
                a1 = fmaf(wt.g[j], sv[j + 1], a1);
                a2 = fmaf(wt.g[j], sv[j + 2], a2);
                a3 = fmaf(wt.g[j], sv[j + 3], a3);
            }
            wc.x = a0; wc.y = a1; wc.z = a2; wc.w = a3;
        }
        *(half4*)(oplane + (size_t)(h0 + i) * 256 + w4) = f4_to_h4(wc);
    }
}

// ---------------------------------------------------------------------------
// Pass 2: H-conv (t1 fp16 -> t2 fp16). Lane-local ring march over h,
// chunk 16 (24 iters / 16 outputs, amp 1.5). 9-deep f32 ring, depth-2 load
// pipeline (named cur/nxt/nn). Grid: 1024 blocks x 4 waves = 16 waves/CU —
// this exact shape measured ~9 us as R9's h_pass.
// ---------------------------------------------------------------------------
__global__ __launch_bounds__(256) void h2_pass(const __half* __restrict__ t1,
                                               __half* __restrict__ t2, W9 wt) {
    const int bid = blockIdx.x;
    const int xcd = bid & 7;
    const int k   = bid >> 3;                       // 0..127
    const int z   = xcd * 32 + (k >> 2);
    const int wv  = threadIdx.x >> 6;
    const int h0  = ((k & 3) * 4 + wv) * 16;        // 16 output rows
    const int w4  = (threadIdx.x & 63) * 4;

    const __half* plane  = t1 + (size_t)z * 65536;
    __half*       oplane = t2 + (size_t)z * 65536;

    float4 ring[9];

    half4 cur = *(const half4*)(plane + (size_t)reflect_idx(h0 - 4, 256) * 256 + w4);
    half4 nxt = *(const half4*)(plane + (size_t)reflect_idx(h0 - 3, 256) * 256 + w4);

    #pragma unroll
    for (int i = 0; i < 24; ++i) {
        half4 nn;
        if (i < 22)
            nn = *(const half4*)(plane + (size_t)reflect_idx(h0 - 2 + i, 256) * 256 + w4);

        ring[i % 9] = h4_to_f4(cur);   // row h0-4+i (static index after unroll)

        if (i >= 8) {
            float a0 = 0.f, a1 = 0.f, a2 = 0.f, a3 = 0.f;
            #pragma unroll
            for (int j = 0; j < 9; ++j) {
                const float4 v = ring[(i - 8 + j) % 9];
                a0 = fmaf(wt.g[j], v.x, a0);
                a1 = fmaf(wt.g[j], v.y, a1);
                a2 = fmaf(wt.g[j], v.z, a2);
                a3 = fmaf(wt.g[j], v.w, a3);
            }
            float4 o; o.x = a0; o.y = a1; o.z = a2; o.w = a3;
            *(half4*)(oplane + (size_t)(h0 + i - 8) * 256 + w4) = f4_to_h4(o);
        }

        cur = nxt; nxt = nn;
    }
}

// ---------------------------------------------------------------------------
// Pass 3: D-conv + clip (t2 fp16 + x f32 -> out f32). Thread owns one f4
// column, marches a z-chunk of 16 (24 iters, amp 1.5) with a 9-deep f32
// ring; named-register depth-2 on t2 (cur/nxt/nn) and on x (xCur/xNxt,
// loaded 2 planes ahead — no array-slot hazard). Plain cached loads/stores
// (x is shared with P1 and L3-resident; NT was the R13 regression).
// Grid: 1024 blocks x 4 waves; chunks 2*xcd..2*xcd+1 match the writer band.
// This shape (f32 variant) measured ~15 us in R6.
// ---------------------------------------------------------------------------
__global__ __launch_bounds__(256) void d_clip_pass(const __half* __restrict__ t2,
                                                   const float* __restrict__ x,
                                                   float* __restrict__ out, W9 wt) {
    const int bid   = blockIdx.x;
    const int xcd   = bid & 7;
    const int k     = bid >> 3;                  // 0..127
    const int chunk = xcd * 2 + (k & 1);         // 0..15, XCD-local
    const int tile  = k >> 1;                    // 0..63
    const int z0    = chunk * 16;
    const size_t c4 = (size_t)tile * 256 + threadIdx.x;   // f4-col in plane

    const half4*  t4 = (const half4*)t2;         // plane stride 16384 half4s
    const float4* xp = (const float4*)x;
    float4*       o4 = (float4*)out;

    float4 ring[9];

    half4 cur = t4[(size_t)reflect_idx(z0 - 4, 256) * 16384 + c4];
    half4 nxt = t4[(size_t)reflect_idx(z0 - 3, 256) * 16384 + c4];
    float4 xCur, xNxt;

    #pragma unroll
    for (int i = 0; i < 24; ++i) {
        half4 nn;
        if (i < 22)
            nn = t4[(size_t)reflect_idx(z0 - 2 + i, 256) * 16384 + c4];
        float4 xNew;
        if (i >= 6 && i < 22)   // x plane z0+i-6, consumed at iter i+2
            xNew = xp[(size_t)(z0 + i - 6) * 16384 + c4];

        ring[i % 9] = h4_to_f4(cur);   // plane z0-4+i

        if (i >= 8) {
            const int z = z0 + i - 8;
            float a0 = 0.f, a1 = 0.f, a2 = 0.f, a3 = 0.f;
            #pragma unroll
            for (int j = 0; j < 9; ++j) {
                const float4 v = ring[(i - 8 + j) % 9];
                a0 = fmaf(wt.g[j], v.x, a0);
                a1 = fmaf(wt.g[j], v.y, a1);
                a2 = fmaf(wt.g[j], v.z, a2);
                a3 = fmaf(wt.g[j], v.w, a3);
            }
            const float4 xv = xCur;    // x plane z (loaded at iter i-2)
            float4 r;
            r.x = fmaxf(fminf(xv.x, a0 + CLIPV), a0 - CLIPV);
            r.y = fmaxf(fminf(xv.y, a1 + CLIPV), a1 - CLIPV);
            r.z = fmaxf(fminf(xv.z, a2 + CLIPV), a2 - CLIPV);
            r.w = fmaxf(fminf(xv.w, a3 + CLIPV), a3 - CLIPV);
            o4[(size_t)z * 16384 + c4] = r;
        }

        cur = nxt; nxt = nn;
        xCur = xNxt; xNxt = xNew;
    }
}

extern "C" void kernel_launch(void* const* d_in, const int* in_sizes, int n_in,
                              void* d_out, int out_size, void* d_ws, size_t ws_size,
                              hipStream_t stream) {
    const float* x = (const float*)d_in[0];
    float* out = (float*)d_out;
    __half* t1 = (__half*)d_ws;            // 32 MB
    __half* t2 = t1 + 16777216;            // 32 MB

    // normalized 1-D Gaussian weights (separable form of the reference kernel)
    W9 wt;
    {
        double g[9], s = 0.0;
        const double sigma = 9.0 / 4.0;
        for (int i = 0; i < 9; ++i) {
            double tt = (i - 4.0) / sigma;
            g[i] = exp(-0.5 * tt * tt);
            s += g[i];
        }
        for (int i = 0; i < 9; ++i) wt.g[i] = (float)(g[i] / s);
    }

    w_pass<<<dim3(2048), dim3(256), 0, stream>>>(x, t1, wt);
    h2_pass<<<dim3(1024), dim3(256), 0, stream>>>(t1, t2, wt);
    d_clip_pass<<<dim3(1024), dim3(256), 0, stream>>>(t2, x, out, wt);
}

// Round 15
// 52.985 us; speedup vs baseline: 1.3976x; 1.2329x over previous
//
#include <hip/hip_runtime.h>
#include <hip/hip_fp16.h>
#include <math.h>

#define CLIPV 0.03f

struct W9 { float g[9]; };
struct half4 { __half2 a, b; };   // 8 bytes, 2 VGPRs

__device__ __forceinline__ int reflect_idx(int i, int n) {
    if (i < 0) i = -i;
    if (i >= n) i = 2 * n - 2 - i;
    return i;
}

__device__ __forceinline__ float4 h4_to_f4(half4 v) {
    const float2 ab = __half22float2(v.a), cd = __half22float2(v.b);
    float4 r; r.x = ab.x; r.y = ab.y; r.z = cd.x; r.w = cd.y; return r;
}
__device__ __forceinline__ half4 f4_to_h4(float4 v) {
    half4 r; r.a = __floats2half2_rn(v.x, v.y); r.b = __floats2half2_rn(v.z, v.w);
    return r;
}

// ---------------------------------------------------------------------------
// Pass 1: W-conv + H-conv fused (x f32 -> t2 fp16). Key structural fixes vs
// the 41-us w_pass (R14 post-mortem):
//  - W result goes into the 9-deep H-ring => 9-iteration liveness, which the
//    compiler provably keeps in registers (h2/d_clip precedent).
//  - The 3 overlapping row loads are staged through NAMED depth-2 chains
//    (cX/nX/mX), the pattern that survives regalloc (VGPR 60 kernels), NOT
//    indexed arrays (which R14 showed get demoted; VGPR 32, loads sunk).
//  - __launch_bounds__(256,2) permits ~128 VGPR so the pipeline fits.
// Wave = 16 output rows of one z-plane; 24 iters (load amp 1.5).
// Grid: 1024 blocks x 4 waves; bid&7 = XCD owns z-band [32*xcd, ..+32).
// Edge cols: R5/R7-validated reversed-load select table.
// ---------------------------------------------------------------------------
__global__ __launch_bounds__(256, 2) void wh_pass(const float* __restrict__ x,
                                                  __half* __restrict__ t2, W9 wt) {
    const int bid = blockIdx.x;
    const int xcd = bid & 7;
    const int k   = bid >> 3;                       // 0..127
    const int z   = xcd * 32 + (k >> 2);            // XCD-local z band
    const int wv  = threadIdx.x >> 6;
    const int h0  = ((k & 3) * 4 + wv) * 16;        // 16 output rows
    const int L   = threadIdx.x & 63;
    const int w4  = L * 4;
    const bool l0 = (L == 0), l63 = (L == 63);
    const int offL = l0 ? 1 : (w4 - 4);     // lane 0 loads cols 1..4, reversed
    const int offR = l63 ? 251 : (w4 + 4);  // lane 63 loads 251..254, reversed

    const float* plane  = x  + (size_t)z * 65536;
    __half*      oplane = t2 + (size_t)z * 65536;

    float4 ring[9];

    // named depth-2 staging chains (consume c*, next n*, incoming m*)
    float4 cLf, cCf, cRf, nLf, nCf, nRf;
    {
        const float* r0 = plane + (size_t)reflect_idx(h0 - 4, 256) * 256;
        cLf = *(const float4*)(r0 + offL);
        cCf = *(const float4*)(r0 + w4);
        cRf = *(const float4*)(r0 + offR);
        const float* r1 = plane + (size_t)reflect_idx(h0 - 3, 256) * 256;
        nLf = *(const float4*)(r1 + offL);
        nCf = *(const float4*)(r1 + w4);
        nRf = *(const float4*)(r1 + offR);
    }

    #pragma unroll
    for (int i = 0; i < 24; ++i) {
        float4 mLf, mCf, mRf;
        if (i < 22) {
            const float* row = plane + (size_t)reflect_idx(h0 - 2 + i, 256) * 256;
            mLf = *(const float4*)(row + offL);
            mCf = *(const float4*)(row + w4);
            mRf = *(const float4*)(row + offR);
        }

        // ---- W-conv of row h0-4+i (consumes c* chain) ----
        float sv[12];
        sv[0] = l0 ? cLf.w : cLf.x;   // col -4 -> 4
        sv[1] = l0 ? cLf.z : cLf.y;   // col -3 -> 3
        sv[2] = l0 ? cLf.y : cLf.z;   // col -2 -> 2
        sv[3] = l0 ? cLf.x : cLf.w;   // col -1 -> 1
        sv[4] = cCf.x; sv[5] = cCf.y; sv[6] = cCf.z; sv[7] = cCf.w;
        sv[8]  = l63 ? cRf.w : cRf.x; // col 256 -> 254
        sv[9]  = l63 ? cRf.z : cRf.y; // col 257 -> 253
        sv[10] = l63 ? cRf.y : cRf.z; // col 258 -> 252
        sv[11] = l63 ? cRf.x : cRf.w; // col 259 -> 251

        {
            float a0 = 0.f, a1 = 0.f, a2 = 0.f, a3 = 0.f;
            #pragma unroll
            for (int j = 0; j < 9; ++j) {
                a0 = fmaf(wt.g[j], sv[j],     a0);
                a1 = fmaf(wt.g[j], sv[j + 1], a1);
                a2 = fmaf(wt.g[j], sv[j + 2], a2);
                a3 = fmaf(wt.g[j], sv[j + 3], a3);
            }
            float4 wc; wc.x = a0; wc.y = a1; wc.z = a2; wc.w = a3;
            ring[i % 9] = wc;   // static index after full unroll; 9-iter liveness
        }

        // ---- H-conv once ring holds rows hout-4..hout+4 ----
        if (i >= 8) {
            float a0 = 0.f, a1 = 0.f, a2 = 0.f, a3 = 0.f;
            #pragma unroll
            for (int j = 0; j < 9; ++j) {
                const float4 v = ring[(i - 8 + j) % 9];
                a0 = fmaf(wt.g[j], v.x, a0);
                a1 = fmaf(wt.g[j], v.y, a1);
                a2 = fmaf(wt.g[j], v.z, a2);
                a3 = fmaf(wt.g[j], v.w, a3);
            }
            float4 o; o.x = a0; o.y = a1; o.z = a2; o.w = a3;
            *(half4*)(oplane + (size_t)(h0 + i - 8) * 256 + w4) = f4_to_h4(o);
        }

        cLf = nLf; cCf = nCf; cRf = nRf;
        nLf = mLf; nCf = mCf; nRf = mRf;
    }
}

// ---------------------------------------------------------------------------
// Pass 2: D-conv + clip (t2 fp16 + x f32 -> out f32) — R14 config unchanged
// (passed; ~14 us by subtraction). Thread owns one f4 column, z-chunk 16
// (24 iters, amp 1.5), 9-deep f32 ring; named depth-2 chains on t2 and x.
// Grid: 1024 blocks x 4 waves; chunks 2*xcd..2*xcd+1 match the writer band.
// ---------------------------------------------------------------------------
__global__ __launch_bounds__(256) void d_clip_pass(const __half* __restrict__ t2,
                                                   const float* __restrict__ x,
                                                   float* __restrict__ out, W9 wt) {
    const int bid   = blockIdx.x;
    const int xcd   = bid & 7;
    const int k     = bid >> 3;                  // 0..127
    const int chunk = xcd * 2 + (k & 1);         // 0..15, XCD-local
    const int tile  = k >> 1;                    // 0..63
    const int z0    = chunk * 16;
    const size_t c4 = (size_t)tile * 256 + threadIdx.x;   // f4-col in plane

    const half4*  t4 = (const half4*)t2;         // plane stride 16384 half4s
    const float4* xp = (const float4*)x;
    float4*       o4 = (float4*)out;

    float4 ring[9];

    half4 cur = t4[(size_t)reflect_idx(z0 - 4, 256) * 16384 + c4];
    half4 nxt = t4[(size_t)reflect_idx(z0 - 3, 256) * 16384 + c4];
    float4 xCur, xNxt;

    #pragma unroll
    for (int i = 0; i < 24; ++i) {
        half4 nn;
        if (i < 22)
            nn = t4[(size_t)reflect_idx(z0 - 2 + i, 256) * 16384 + c4];
        float4 xNew;
        if (i >= 6 && i < 22)   // x plane z0+i-6, consumed at iter i+2
            xNew = xp[(size_t)(z0 + i - 6) * 16384 + c4];

        ring[i % 9] = h4_to_f4(cur);   // plane z0-4+i

        if (i >= 8) {
            const int z = z0 + i - 8;
            float a0 = 0.f, a1 = 0.f, a2 = 0.f, a3 = 0.f;
            #pragma unroll
            for (int j = 0; j < 9; ++j) {
                const float4 v = ring[(i - 8 + j) % 9];
                a0 = fmaf(wt.g[j], v.x, a0);
                a1 = fmaf(wt.g[j], v.y, a1);
                a2 = fmaf(wt.g[j], v.z, a2);
                a3 = fmaf(wt.g[j], v.w, a3);
            }
            const float4 xv = xCur;    // x plane z (loaded at iter i-2)
            float4 r;
            r.x = fmaxf(fminf(xv.x, a0 + CLIPV), a0 - CLIPV);
            r.y = fmaxf(fminf(xv.y, a1 + CLIPV), a1 - CLIPV);
            r.z = fmaxf(fminf(xv.z, a2 + CLIPV), a2 - CLIPV);
            r.w = fmaxf(fminf(xv.w, a3 + CLIPV), a3 - CLIPV);
            o4[(size_t)z * 16384 + c4] = r;
        }

        cur = nxt; nxt = nn;
        xCur = xNxt; xNxt = xNew;
    }
}

extern "C" void kernel_launch(void* const* d_in, const int* in_sizes, int n_in,
                              void* d_out, int out_size, void* d_ws, size_t ws_size,
                              hipStream_t stream) {
    const float* x = (const float*)d_in[0];
    float* out = (float*)d_out;
    __half* t2 = (__half*)d_ws;            // 32 MB (single fp16 intermediate)

    // normalized 1-D Gaussian weights (separable form of the reference kernel)
    W9 wt;
    {
        double g[9], s = 0.0;
        const double sigma = 9.0 / 4.0;
        for (int i = 0; i < 9; ++i) {
            double tt = (i - 4.0) / sigma;
            g[i] = exp(-0.5 * tt * tt);
            s += g[i];
        }
        for (int i = 0; i < 9; ++i) wt.g[i] = (float)(g[i] / s);
    }

    wh_pass<<<dim3(1024), dim3(256), 0, stream>>>(x, t2, wt);
    d_clip_pass<<<dim3(1024), dim3(256), 0, stream>>>(t2, x, out, wt);
}

// Round 16
// 52.745 us; speedup vs baseline: 1.4040x; 1.0045x over previous
//
#include <hip/hip_runtime.h>
#include <hip/hip_fp16.h>
#include <math.h>

#define CLIPV 0.03f

struct W9 { float g[9]; };
struct half4 { __half2 a, b; };   // 8 bytes, 2 VGPRs

__device__ __forceinline__ int reflect_idx(int i, int n) {
    if (i < 0) i = -i;
    if (i >= n) i = 2 * n - 2 - i;
    return i;
}

__device__ __forceinline__ float4 h4_to_f4(half4 v) {
    const float2 ab = __half22float2(v.a), cd = __half22float2(v.b);
    float4 r; r.x = ab.x; r.y = ab.y; r.z = cd.x; r.w = cd.y; return r;
}
__device__ __forceinline__ half4 f4_to_h4(float4 v) {
    half4 r; r.a = __floats2half2_rn(v.x, v.y); r.b = __floats2half2_rn(v.z, v.w);
    return r;
}

// ---------------------------------------------------------------------------
// Pass 1: W-conv + H-conv fused (x f32 -> t2 fp16).
// R16 change vs R15: __launch_bounds__(256, 4) — the 2nd arg is min waves/EU,
// so 4 => 4 blocks/CU => VGPR cap 128. R15's (256,2) allowed up to ~256 VGPR,
// letting the fully-unrolled 24-iter loop balloon past 128 and HALVING
// occupancy to 8 waves/CU — cancelling the named-chain prefetch win.
// Budget check: ring 36 + staging chains 24 (c*/n*) + 12 in-flight (m*)
// + sv/acc/addr ~30 => ~100-120 VGPR, fits under 128 at 4 waves/SIMD.
// Wave = 16 output rows of one z-plane; 24 iters (load amp 1.5).
// Grid: 1024 blocks x 4 waves = 4096 waves = 16 waves/CU exactly.
// bid&7 = XCD owns z-band [32*xcd, ..+32).
// ---------------------------------------------------------------------------
__global__ __launch_bounds__(256, 4) void wh_pass(const float* __restrict__ x,
                                                  __half* __restrict__ t2, W9 wt) {
    const int bid = blockIdx.x;
    const int xcd = bid & 7;
    const int k   = bid >> 3;                       // 0..127
    const int z   = xcd * 32 + (k >> 2);            // XCD-local z band
    const int wv  = threadIdx.x >> 6;
    const int h0  = ((k & 3) * 4 + wv) * 16;        // 16 output rows
    const int L   = threadIdx.x & 63;
    const int w4  = L * 4;
    const bool l0 = (L == 0), l63 = (L == 63);
    const int offL = l0 ? 1 : (w4 - 4);     // lane 0 loads cols 1..4, reversed
    const int offR = l63 ? 251 : (w4 + 4);  // lane 63 loads 251..254, reversed

    const float* plane  = x  + (size_t)z * 65536;
    __half*      oplane = t2 + (size_t)z * 65536;

    float4 ring[9];

    // named depth-2 staging chains (consume c*, next n*, incoming m*)
    float4 cLf, cCf, cRf, nLf, nCf, nRf;
    {
        const float* r0 = plane + (size_t)reflect_idx(h0 - 4, 256) * 256;
        cLf = *(const float4*)(r0 + offL);
        cCf = *(const float4*)(r0 + w4);
        cRf = *(const float4*)(r0 + offR);
        const float* r1 = plane + (size_t)reflect_idx(h0 - 3, 256) * 256;
        nLf = *(const float4*)(r1 + offL);
        nCf = *(const float4*)(r1 + w4);
        nRf = *(const float4*)(r1 + offR);
    }

    #pragma unroll
    for (int i = 0; i < 24; ++i) {
        float4 mLf, mCf, mRf;
        if (i < 22) {
            const float* row = plane + (size_t)reflect_idx(h0 - 2 + i, 256) * 256;
            mLf = *(const float4*)(row + offL);
            mCf = *(const float4*)(row + w4);
            mRf = *(const float4*)(row + offR);
        }

        // ---- W-conv of row h0-4+i (consumes c* chain) ----
        float sv[12];
        sv[0] = l0 ? cLf.w : cLf.x;   // col -4 -> 4
        sv[1] = l0 ? cLf.z : cLf.y;   // col -3 -> 3
        sv[2] = l0 ? cLf.y : cLf.z;   // col -2 -> 2
        sv[3] = l0 ? cLf.x : cLf.w;   // col -1 -> 1
        sv[4] = cCf.x; sv[5] = cCf.y; sv[6] = cCf.z; sv[7] = cCf.w;
        sv[8]  = l63 ? cRf.w : cRf.x; // col 256 -> 254
        sv[9]  = l63 ? cRf.z : cRf.y; // col 257 -> 253
        sv[10] = l63 ? cRf.y : cRf.z; // col 258 -> 252
        sv[11] = l63 ? cRf.x : cRf.w; // col 259 -> 251

        {
            float a0 = 0.f, a1 = 0.f, a2 = 0.f, a3 = 0.f;
            #pragma unroll
            for (int j = 0; j < 9; ++j) {
                a0 = fmaf(wt.g[j], sv[j],     a0);
                a1 = fmaf(wt.g[j], sv[j + 1], a1);
                a2 = fmaf(wt.g[j], sv[j + 2], a2);
                a3 = fmaf(wt.g[j], sv[j + 3], a3);
            }
            float4 wc; wc.x = a0; wc.y = a1; wc.z = a2; wc.w = a3;
            ring[i % 9] = wc;   // static index after full unroll; 9-iter liveness
        }

        // ---- H-conv once ring holds rows hout-4..hout+4 ----
        if (i >= 8) {
            float a0 = 0.f, a1 = 0.f, a2 = 0.f, a3 = 0.f;
            #pragma unroll
            for (int j = 0; j < 9; ++j) {
                const float4 v = ring[(i - 8 + j) % 9];
                a0 = fmaf(wt.g[j], v.x, a0);
                a1 = fmaf(wt.g[j], v.y, a1);
                a2 = fmaf(wt.g[j], v.z, a2);
                a3 = fmaf(wt.g[j], v.w, a3);
            }
            float4 o; o.x = a0; o.y = a1; o.z = a2; o.w = a3;
            *(half4*)(oplane + (size_t)(h0 + i - 8) * 256 + w4) = f4_to_h4(o);
        }

        cLf = nLf; cCf = nCf; cRf = nRf;
        nLf = mLf; nCf = mCf; nRf = mRf;
    }
}

// ---------------------------------------------------------------------------
// Pass 2: D-conv + clip (t2 fp16 + x f32 -> out f32) — unchanged from R14/R15
// (measured ~14 us, VGPR 60). Thread owns one f4 column, z-chunk 16 (24
// iters, amp 1.5), 9-deep f32 ring; named depth-2 chains on t2 and x.
// Grid: 1024 blocks x 4 waves; chunks 2*xcd..2*xcd+1 match the writer band.
// ---------------------------------------------------------------------------
__global__ __launch_bounds__(256) void d_clip_pass(const __half* __restrict__ t2,
                                                   const float* __restrict__ x,
                                                   float* __restrict__ out, W9 wt) {
    const int bid   = blockIdx.x;
    const int xcd   = bid & 7;
    const int k     = bid >> 3;                  // 0..127
    const int chunk = xcd * 2 + (k & 1);         // 0..15, XCD-local
    const int tile  = k >> 1;                    // 0..63
    const int z0    = chunk * 16;
    const size_t c4 = (size_t)tile * 256 + threadIdx.x;   // f4-col in plane

    const half4*  t4 = (const half4*)t2;         // plane stride 16384 half4s
    const float4* xp = (const float4*)x;
    float4*       o4 = (float4*)out;

    float4 ring[9];

    half4 cur = t4[(size_t)reflect_idx(z0 - 4, 256) * 16384 + c4];
    half4 nxt = t4[(size_t)reflect_idx(z0 - 3, 256) * 16384 + c4];
    float4 xCur, xNxt;

    #pragma unroll
    for (int i = 0; i < 24; ++i) {
        half4 nn;
        if (i < 22)
            nn = t4[(size_t)reflect_idx(z0 - 2 + i, 256) * 16384 + c4];
        float4 xNew;
        if (i >= 6 && i < 22)   // x plane z0+i-6, consumed at iter i+2
            xNew = xp[(size_t)(z0 + i - 6) * 16384 + c4];

        ring[i % 9] = h4_to_f4(cur);   // plane z0-4+i

        if (i >= 8) {
            const int z = z0 + i - 8;
            float a0 = 0.f, a1 = 0.f, a2 = 0.f, a3 = 0.f;
            #pragma unroll
            for (int j = 0; j < 9; ++j) {
                const float4 v = ring[(i - 8 + j) % 9];
                a0 = fmaf(wt.g[j], v.x, a0);
                a1 = fmaf(wt.g[j], v.y, a1);
                a2 = fmaf(wt.g[j], v.z, a2);
                a3 = fmaf(wt.g[j], v.w, a3);
            }
            const float4 xv = xCur;    // x plane z (loaded at iter i-2)
            float4 r;
            r.x = fmaxf(fminf(xv.x, a0 + CLIPV), a0 - CLIPV);
            r.y = fmaxf(fminf(xv.y, a1 + CLIPV), a1 - CLIPV);
            r.z = fmaxf(fminf(xv.z, a2 + CLIPV), a2 - CLIPV);
            r.w = fmaxf(fminf(xv.w, a3 + CLIPV), a3 - CLIPV);
            o4[(size_t)z * 16384 + c4] = r;
        }

        cur = nxt; nxt = nn;
        xCur = xNxt; xNxt = xNew;
    }
}

extern "C" void kernel_launch(void* const* d_in, const int* in_sizes, int n_in,
                              void* d_out, int out_size, void* d_ws, size_t ws_size,
                              hipStream_t stream) {
    const float* x = (const float*)d_in[0];
    float* out = (float*)d_out;
    __half* t2 = (__half*)d_ws;            // 32 MB (single fp16 intermediate)

    // normalized 1-D Gaussian weights (separable form of the reference kernel)
    W9 wt;
    {
        double g[9], s = 0.0;
        const double sigma = 9.0 / 4.0;
        for (int i = 0; i < 9; ++i) {
            double tt = (i - 4.0) / sigma;
            g[i] = exp(-0.5 * tt * tt);
            s += g[i];
        }
        for (int i = 0; i < 9; ++i) wt.g[i] = (float)(g[i] / s);
    }

    wh_pass<<<dim3(1024), dim3(256), 0, stream>>>(x, t2, wt);
    d_clip_pass<<<dim3(1024), dim3(256), 0, stream>>>(t2, x, out, wt);
}